// Round 1
// 188.035 us; speedup vs baseline: 1.1408x; 1.1408x over previous
//
#include <hip/hip_runtime.h>
#include <stdint.h>

#define DIM   128
#define KCOLS 65536
#define BB    1024
#define LL    512
#define PSZ   8388608
#define INV_T (1.0f / 0.09f)
#define MOM   0.7f

// output layout (float32 elements, concatenated in return order)
#define OUT_LOGITS 0
#define OUT_LABELS (BB * LL)                    // 524288
#define OUT_QUEUE  (BB * LL + BB)               // 525312
#define OUT_PARAMK (BB * LL + BB + DIM * KCOLS) // 8913920

// ws layout (bytes)
#define WS_QT 0   // bf16 queueT [KCOLS][DIM] = 16 MiB

__device__ inline unsigned short f32_to_bf16(float f) {
    uint32_t u = __float_as_uint(f);
    uint32_t r = (u + 0x7fffu + ((u >> 16) & 1u)) >> 16;
    return (unsigned short)r;
}

// Fused: read queue once (float4-coalesced); write new_queue (float4) AND
// bf16 transposed qt[KCOLS][DIM] (uint4 rows), via LDS tile.
// Key normalization is done INLINE (cooperatively, tiny invn_s LDS) for the
// <=16 blocks whose column range intersects [start, start+BB) -- this
// removes the separate norm_kernel launch and the kn workspace round-trip.
__global__ void __launch_bounds__(256)
queue_fused_kernel(const float* __restrict__ queue,
                   const float* __restrict__ keys,
                   const int* __restrict__ ptr_p,
                   float* __restrict__ outq,
                   unsigned short* __restrict__ qt) {
    __shared__ float tile[64][DIM + 1];  // [k][d], ~33 KB
    __shared__ float invn_s[64];
    int k0 = blockIdx.x * 64;
    int t  = threadIdx.x;
    int ptr   = ptr_p[0];
    int start = min(max(ptr, 0), KCOLS - BB);  // dynamic_update_slice clamp

    // cooperative inv-norms for the key rows this block will write (if any)
    {
        int row_local = t >> 2;       // 0..63 -> column k0+row_local
        int l4        = t & 3;        // 32-dim slice
        int c = k0 + row_local;
        if (c >= start && c < start + BB) {
            const float4* kr =
                (const float4*)&keys[(size_t)(c - start) * DIM + l4 * 32];
            float s = 0.f;
#pragma unroll
            for (int i = 0; i < 8; ++i) {
                float4 v = kr[i];
                s += v.x * v.x + v.y * v.y + v.z * v.z + v.w * v.w;
            }
            s += __shfl_xor(s, 1, 64);
            s += __shfl_xor(s, 2, 64);
            if (l4 == 0) invn_s[row_local] = 1.0f / sqrtf(s);
        }
    }
    __syncthreads();

    int lane16 = t & 15;
    int hi     = t >> 4;       // 0..15
    int kq     = lane16 * 4;   // column offset within tile, step 4
#pragma unroll
    for (int p = 0; p < 8; ++p) {
        int d = p * 16 + hi;
        float4 v = *(const float4*)&queue[(size_t)d * KCOLS + k0 + kq];
        float vv[4] = {v.x, v.y, v.z, v.w};
#pragma unroll
        for (int j = 0; j < 4; ++j) {
            tile[kq + j][d] = vv[j];           // original value for qt
            int col = k0 + kq + j;
            if (col >= start && col < start + BB)
                vv[j] = keys[(size_t)(col - start) * DIM + d] * invn_s[kq + j];
        }
        float4 w = {vv[0], vv[1], vv[2], vv[3]};
        *(float4*)&outq[(size_t)d * KCOLS + k0 + kq] = w;
    }
    __syncthreads();
    // transpose out: each lane packs 8 consecutive d of one k-row -> uint4
    int d0 = lane16 * 8;
#pragma unroll
    for (int ki = 0; ki < 4; ++ki) {
        int kl = hi + ki * 16;  // 0..63
        float f[8];
#pragma unroll
        for (int j = 0; j < 8; ++j) f[j] = tile[kl][d0 + j];
        uint4 o;
        o.x = (uint32_t)f32_to_bf16(f[0]) | ((uint32_t)f32_to_bf16(f[1]) << 16);
        o.y = (uint32_t)f32_to_bf16(f[2]) | ((uint32_t)f32_to_bf16(f[3]) << 16);
        o.z = (uint32_t)f32_to_bf16(f[4]) | ((uint32_t)f32_to_bf16(f[5]) << 16);
        o.w = (uint32_t)f32_to_bf16(f[6]) | ((uint32_t)f32_to_bf16(f[7]) << 16);
        *(uint4*)&qt[(size_t)(k0 + kl) * DIM + d0] = o;
    }
}

// 8-term bf16 dot-accumulate against a qreg slice
#define DOT8(uu, qo, dst) {                                    \
    float acc = 0.f;                                           \
    acc += qreg[(qo) + 0] * __uint_as_float((uu).x << 16);     \
    acc += qreg[(qo) + 1] * __uint_as_float((uu).x & 0xffff0000u); \
    acc += qreg[(qo) + 2] * __uint_as_float((uu).y << 16);     \
    acc += qreg[(qo) + 3] * __uint_as_float((uu).y & 0xffff0000u); \
    acc += qreg[(qo) + 4] * __uint_as_float((uu).z << 16);     \
    acc += qreg[(qo) + 5] * __uint_as_float((uu).z & 0xffff0000u); \
    acc += qreg[(qo) + 6] * __uint_as_float((uu).w << 16);     \
    acc += qreg[(qo) + 7] * __uint_as_float((uu).w & 0xffff0000u); \
    (dst) = acc; }

// Fused logits + momentum-param update.
// Blocks [0, BB):      one block per batch row b. q[b] is normalized
//                      in-register (1/T folded in). Each 4-lane quartet owns
//                      8 gathers with a rolling 4-deep uint4 load window ->
//                      16 independent 16B loads in flight (latency hiding by
//                      ILP, no filter phase, no LDS atomics).
// Blocks [BB, BB+8192): streaming momentum update (idle-BW co-resident with
//                      the latency-bound gather blocks) + labels.
__global__ void __launch_bounds__(256)
logits_param_kernel(const float* __restrict__ q,
                    const unsigned short* __restrict__ qt,
                    const int* __restrict__ sidx,
                    const float* __restrict__ pq,
                    const float* __restrict__ pk,
                    float* __restrict__ out) {
    int t = threadIdx.x;

    if (blockIdx.x >= BB) {
        // ---- momentum param path ----
        int gid  = (blockIdx.x - BB) * 256 + t;
        float4 a = ((const float4*)pq)[gid];
        float4 c = ((const float4*)pk)[gid];
        float4 r;
        r.x = c.x * MOM + a.x * (1.0f - MOM);
        r.y = c.y * MOM + a.y * (1.0f - MOM);
        r.z = c.z * MOM + a.z * (1.0f - MOM);
        r.w = c.w * MOM + a.w * (1.0f - MOM);
        ((float4*)(out + OUT_PARAMK))[gid] = r;
        if (gid < BB) out[OUT_LABELS + gid] = 0.0f;
        return;
    }

    // ---- logits path ----
    int b = blockIdx.x;
    __shared__ int sl[LL];
#pragma unroll
    for (int l = t; l < LL; l += 256) sl[l] = sidx[b * LL + l];

    int quarter = t & 3;   // 32-dim chunk
    int grp     = t >> 2;  // 0..63: which l-slot within each pass

    // normalize q[b] in-register; fold 1/T into the coefficients
    float qreg[32];
    {
        const float4* qb = (const float4*)(q + (size_t)b * DIM + quarter * 32);
        float s = 0.f;
#pragma unroll
        for (int i = 0; i < 8; ++i) {
            float4 v = qb[i];
            qreg[4 * i + 0] = v.x; qreg[4 * i + 1] = v.y;
            qreg[4 * i + 2] = v.z; qreg[4 * i + 3] = v.w;
            s += v.x * v.x + v.y * v.y + v.z * v.z + v.w * v.w;
        }
        s += __shfl_xor(s, 1, 64);
        s += __shfl_xor(s, 2, 64);
        float inv = rsqrtf(s) * INV_T;
#pragma unroll
        for (int i = 0; i < 32; ++i) qreg[i] *= inv;
    }
    __syncthreads();

    // this quartet's 8 gather indices (LDS broadcast reads)
    int idxs[8];
#pragma unroll
    for (int e = 0; e < 8; ++e) idxs[e] = sl[grp + (e << 6)];

    // rolling 4-deep window of gathered rows (quartet covers 256B row)
    uint4 u[4][4];
#pragma unroll
    for (int e = 0; e < 4; ++e) {
        const uint4* p = (const uint4*)(qt + (size_t)idxs[e] * DIM) + quarter * 4;
        u[e][0] = p[0]; u[e][1] = p[1]; u[e][2] = p[2]; u[e][3] = p[3];
    }
#pragma unroll
    for (int e = 0; e < 8; ++e) {
        const int slot = e & 3;
        uint4 t0 = u[slot][0], t1 = u[slot][1], t2 = u[slot][2], t3 = u[slot][3];
        if (e < 4) {  // refill the slot we just drained (consumed 3 iters later)
            const uint4* p =
                (const uint4*)(qt + (size_t)idxs[e + 4] * DIM) + quarter * 4;
            u[slot][0] = p[0]; u[slot][1] = p[1];
            u[slot][2] = p[2]; u[slot][3] = p[3];
        }
        float s0, s1, s2, s3;
        DOT8(t0,  0, s0);
        DOT8(t1,  8, s1);
        DOT8(t2, 16, s2);
        DOT8(t3, 24, s3);
        float s = (s0 + s1) + (s2 + s3);
        s += __shfl_xor(s, 1, 64);
        s += __shfl_xor(s, 2, 64);
        if (quarter == 0)
            out[OUT_LOGITS + (size_t)b * LL + grp + (e << 6)] = s;
    }
}

extern "C" void kernel_launch(void* const* d_in, const int* in_sizes, int n_in,
                              void* d_out, int out_size, void* d_ws, size_t ws_size,
                              hipStream_t stream) {
    const float* q     = (const float*)d_in[0];
    const float* queue = (const float*)d_in[1];
    const float* keys  = (const float*)d_in[2];
    const float* pq    = (const float*)d_in[3];
    const float* pk    = (const float*)d_in[4];
    const int*   sidx  = (const int*)d_in[5];
    const int*   ptr_p = (const int*)d_in[6];
    float* out = (float*)d_out;

    unsigned short* ws_qt = (unsigned short*)((char*)d_ws + WS_QT);

    // 1) fused queue copy/overwrite (inline key-norm) + bf16 transpose
    queue_fused_kernel<<<KCOLS / 64, 256, 0, stream>>>(queue, keys, ptr_p,
                                                       out + OUT_QUEUE, ws_qt);
    // 2) fused gathered dot products (inline q-norm) + momentum param update
    logits_param_kernel<<<BB + PSZ / 1024, 256, 0, stream>>>(q, ws_qt, sidx,
                                                             pq, pk, out);
}

// Round 2
// 182.897 us; speedup vs baseline: 1.1729x; 1.0281x over previous
//
#include <hip/hip_runtime.h>
#include <stdint.h>

#define DIM   128
#define KCOLS 65536
#define BB    1024
#define LL    512
#define PSZ   8388608
#define INV_T (1.0f / 0.09f)
#define MOM   0.7f

// output layout (float32 elements, concatenated in return order)
#define OUT_LOGITS 0
#define OUT_LABELS (BB * LL)                    // 524288
#define OUT_QUEUE  (BB * LL + BB)               // 525312
#define OUT_PARAMK (BB * LL + BB + DIM * KCOLS) // 8913920

// ws layout (bytes)
#define WS_QT 0   // bf16 queueT [KCOLS][DIM] = 16 MiB

__device__ inline unsigned short f32_to_bf16(float f) {
    uint32_t u = __float_as_uint(f);
    uint32_t r = (u + 0x7fffu + ((u >> 16) & 1u)) >> 16;
    return (unsigned short)r;
}

// Fused: read queue once (float4-coalesced); write new_queue (float4) AND
// bf16 transposed qt[KCOLS][DIM] (uint4 rows), via LDS tile.
// Key normalization is done INLINE (cooperatively) for the <=16 blocks whose
// column range intersects [start, start+BB).
__global__ void __launch_bounds__(256)
queue_fused_kernel(const float* __restrict__ queue,
                   const float* __restrict__ keys,
                   const int* __restrict__ ptr_p,
                   float* __restrict__ outq,
                   unsigned short* __restrict__ qt) {
    __shared__ float tile[64][DIM + 1];  // [k][d], ~33 KB
    __shared__ float invn_s[64];
    int k0 = blockIdx.x * 64;
    int t  = threadIdx.x;
    int ptr   = ptr_p[0];
    int start = min(max(ptr, 0), KCOLS - BB);  // dynamic_update_slice clamp

    // cooperative inv-norms for the key rows this block will write (if any)
    {
        int row_local = t >> 2;       // 0..63 -> column k0+row_local
        int l4        = t & 3;        // 32-dim slice
        int c = k0 + row_local;
        if (c >= start && c < start + BB) {
            const float4* kr =
                (const float4*)&keys[(size_t)(c - start) * DIM + l4 * 32];
            float s = 0.f;
#pragma unroll
            for (int i = 0; i < 8; ++i) {
                float4 v = kr[i];
                s += v.x * v.x + v.y * v.y + v.z * v.z + v.w * v.w;
            }
            s += __shfl_xor(s, 1, 64);
            s += __shfl_xor(s, 2, 64);
            if (l4 == 0) invn_s[row_local] = 1.0f / sqrtf(s);
        }
    }
    __syncthreads();

    int lane16 = t & 15;
    int hi     = t >> 4;       // 0..15
    int kq     = lane16 * 4;   // column offset within tile, step 4
#pragma unroll
    for (int p = 0; p < 8; ++p) {
        int d = p * 16 + hi;
        float4 v = *(const float4*)&queue[(size_t)d * KCOLS + k0 + kq];
        float vv[4] = {v.x, v.y, v.z, v.w};
#pragma unroll
        for (int j = 0; j < 4; ++j) {
            tile[kq + j][d] = vv[j];           // original value for qt
            int col = k0 + kq + j;
            if (col >= start && col < start + BB)
                vv[j] = keys[(size_t)(col - start) * DIM + d] * invn_s[kq + j];
        }
        float4 w = {vv[0], vv[1], vv[2], vv[3]};
        *(float4*)&outq[(size_t)d * KCOLS + k0 + kq] = w;
    }
    __syncthreads();
    // transpose out: each lane packs 8 consecutive d of one k-row -> uint4
    int d0 = lane16 * 8;
#pragma unroll
    for (int ki = 0; ki < 4; ++ki) {
        int kl = hi + ki * 16;  // 0..63
        float f[8];
#pragma unroll
        for (int j = 0; j < 8; ++j) f[j] = tile[kl][d0 + j];
        uint4 o;
        o.x = (uint32_t)f32_to_bf16(f[0]) | ((uint32_t)f32_to_bf16(f[1]) << 16);
        o.y = (uint32_t)f32_to_bf16(f[2]) | ((uint32_t)f32_to_bf16(f[3]) << 16);
        o.z = (uint32_t)f32_to_bf16(f[4]) | ((uint32_t)f32_to_bf16(f[5]) << 16);
        o.w = (uint32_t)f32_to_bf16(f[6]) | ((uint32_t)f32_to_bf16(f[7]) << 16);
        *(uint4*)&qt[(size_t)(k0 + kl) * DIM + d0] = o;
    }
}

// 8-term bf16 dot-accumulate against a qreg slice
#define DOT8(uu, qo, dst) {                                    \
    float acc = 0.f;                                           \
    acc += qreg[(qo) + 0] * __uint_as_float((uu).x << 16);     \
    acc += qreg[(qo) + 1] * __uint_as_float((uu).x & 0xffff0000u); \
    acc += qreg[(qo) + 2] * __uint_as_float((uu).y << 16);     \
    acc += qreg[(qo) + 3] * __uint_as_float((uu).y & 0xffff0000u); \
    acc += qreg[(qo) + 4] * __uint_as_float((uu).z << 16);     \
    acc += qreg[(qo) + 5] * __uint_as_float((uu).z & 0xffff0000u); \
    acc += qreg[(qo) + 6] * __uint_as_float((uu).w << 16);     \
    acc += qreg[(qo) + 7] * __uint_as_float((uu).w & 0xffff0000u); \
    (dst) = acc; }

// Fused logits + momentum-param update, 1:8 DISPATCH-STRIPED so every CU
// holds a mix of latency-bound gather waves and BW-streaming param waves
// for the whole dispatch (no serialized phases).
//   bid % 9 == 0  -> logits row b = bid/9          (1024 blocks)
//   else          -> param chunk  c = (bid/9)*8 + bid%9 - 1   (8192 blocks)
// Gather addressing is LINE-COALESCED: for each gather instruction a
// quartet's 4 lanes read quarter*16B within ONE 64B segment (slot-major),
// so each instruction touches 16 cache lines (one per quartet), 100%
// line utilization -- vs 64 lines / 25% utilization in the old layout.
__global__ void __launch_bounds__(256)
logits_param_kernel(const float* __restrict__ q,
                    const unsigned short* __restrict__ qt,
                    const int* __restrict__ sidx,
                    const float* __restrict__ pq,
                    const float* __restrict__ pk,
                    float* __restrict__ out) {
    int t   = threadIdx.x;
    int bid = blockIdx.x;
    int g   = bid / 9;
    int rem = bid - g * 9;

    if (rem != 0) {
        // ---- momentum param path ----
        int gid  = (g * 8 + rem - 1) * 256 + t;
        float4 a = ((const float4*)pq)[gid];
        float4 c = ((const float4*)pk)[gid];
        float4 r;
        r.x = c.x * MOM + a.x * (1.0f - MOM);
        r.y = c.y * MOM + a.y * (1.0f - MOM);
        r.z = c.z * MOM + a.z * (1.0f - MOM);
        r.w = c.w * MOM + a.w * (1.0f - MOM);
        ((float4*)(out + OUT_PARAMK))[gid] = r;
        if (gid < BB) out[OUT_LABELS + gid] = 0.0f;
        return;
    }

    // ---- logits path ----
    int b = g;
    __shared__ int sl[LL];
#pragma unroll
    for (int l = t; l < LL; l += 256) sl[l] = sidx[b * LL + l];

    int quarter = t & 3;   // which 16B piece of each 64B segment
    int grp     = t >> 2;  // 0..63: which l-slot within each pass

    // normalize q[b] in-register; fold 1/T in.
    // Lane holds dims  j*32 + quarter*8 + {0..7}  for j = 0..3
    // (matches the slot-major gather layout below).
    float qreg[32];
    {
        const float* qb = q + (size_t)b * DIM;
        float s = 0.f;
#pragma unroll
        for (int j = 0; j < 4; ++j) {
            const float4* pp = (const float4*)(qb + j * 32 + quarter * 8);
            float4 v0 = pp[0], v1 = pp[1];
            qreg[j * 8 + 0] = v0.x; qreg[j * 8 + 1] = v0.y;
            qreg[j * 8 + 2] = v0.z; qreg[j * 8 + 3] = v0.w;
            qreg[j * 8 + 4] = v1.x; qreg[j * 8 + 5] = v1.y;
            qreg[j * 8 + 6] = v1.z; qreg[j * 8 + 7] = v1.w;
            s += v0.x * v0.x + v0.y * v0.y + v0.z * v0.z + v0.w * v0.w;
            s += v1.x * v1.x + v1.y * v1.y + v1.z * v1.z + v1.w * v1.w;
        }
        s += __shfl_xor(s, 1, 64);
        s += __shfl_xor(s, 2, 64);
        float inv = rsqrtf(s) * INV_T;
#pragma unroll
        for (int i = 0; i < 32; ++i) qreg[i] *= inv;
    }
    __syncthreads();

    // this quartet's 8 gather indices (LDS broadcast reads)
    int idxs[8];
#pragma unroll
    for (int e = 0; e < 8; ++e) idxs[e] = sl[grp + (e << 6)];

    // rolling 4-deep window; entry e's row read as 4 slot-major uint4s:
    // lane address = idx*256B + j*64B + quarter*16B
    uint4 u[4][4];
#pragma unroll
    for (int e = 0; e < 4; ++e) {
        const uint4* p = (const uint4*)(qt + (size_t)idxs[e] * DIM) + quarter;
        u[e][0] = p[0]; u[e][1] = p[4]; u[e][2] = p[8]; u[e][3] = p[12];
    }
#pragma unroll
    for (int e = 0; e < 8; ++e) {
        const int slot = e & 3;
        uint4 t0 = u[slot][0], t1 = u[slot][1], t2 = u[slot][2], t3 = u[slot][3];
        if (e < 4) {  // refill the slot just drained (consumed at e+4)
            const uint4* p =
                (const uint4*)(qt + (size_t)idxs[e + 4] * DIM) + quarter;
            u[slot][0] = p[0]; u[slot][1] = p[4];
            u[slot][2] = p[8]; u[slot][3] = p[12];
        }
        float s0, s1, s2, s3;
        DOT8(t0,  0, s0);
        DOT8(t1,  8, s1);
        DOT8(t2, 16, s2);
        DOT8(t3, 24, s3);
        float s = (s0 + s1) + (s2 + s3);
        s += __shfl_xor(s, 1, 64);
        s += __shfl_xor(s, 2, 64);
        if (quarter == 0)
            out[OUT_LOGITS + (size_t)b * LL + grp + (e << 6)] = s;
    }
}

extern "C" void kernel_launch(void* const* d_in, const int* in_sizes, int n_in,
                              void* d_out, int out_size, void* d_ws, size_t ws_size,
                              hipStream_t stream) {
    const float* q     = (const float*)d_in[0];
    const float* queue = (const float*)d_in[1];
    const float* keys  = (const float*)d_in[2];
    const float* pq    = (const float*)d_in[3];
    const float* pk    = (const float*)d_in[4];
    const int*   sidx  = (const int*)d_in[5];
    const int*   ptr_p = (const int*)d_in[6];
    float* out = (float*)d_out;

    unsigned short* ws_qt = (unsigned short*)((char*)d_ws + WS_QT);

    // 1) fused queue copy/overwrite (inline key-norm) + bf16 transpose
    queue_fused_kernel<<<KCOLS / 64, 256, 0, stream>>>(queue, keys, ptr_p,
                                                       out + OUT_QUEUE, ws_qt);
    // 2) striped fused gathered dot products + momentum param update
    logits_param_kernel<<<9 * BB, 256, 0, stream>>>(q, ws_qt, sidx,
                                                    pq, pk, out);
}